// Round 16
// baseline (180.163 us; speedup 1.0000x reference)
//
#include <hip/hip_runtime.h>
#include <hip/hip_cooperative_groups.h>
namespace cg = cooperative_groups;

#define NT 64
#define NBMAX1 1024   // max buckets for the fast path (nodes <= 65536)
#define CAPB 2048     // payload slots per bucket (mean ~1279 here)
#define CHUNK 4096    // edges per fill block
#define FTHR 512      // threads for fast-path kernels

typedef short bf16x8 __attribute__((ext_vector_type(8)));
typedef float f32x4  __attribute__((ext_vector_type(4)));

__device__ __forceinline__ unsigned short f2bf(float f) {
    unsigned u = __builtin_bit_cast(unsigned, f);
    unsigned r = (u + 0x7fffu + ((u >> 16) & 1u)) >> 16;   // round-nearest-even
    return (unsigned short)r;
}
__device__ __forceinline__ float bf2f(unsigned short h) {
    return __builtin_bit_cast(float, (unsigned)h << 16);
}
__device__ __forceinline__ unsigned pack2(float a, float b) {
    return (unsigned)f2bf(a) | ((unsigned)f2bf(b) << 16);
}

// ===========================================================================
// Cooperative mega-kernel: prep+hist -> scan -> fill ∥ gemm -> gather,
// one dispatch, grid.sync() between phases (device-scope fences handle
// cross-XCD visibility). 512 threads/block, 56KB LDS union (2 blocks/CU).
// ===========================================================================
__global__ __launch_bounds__(FTHR) void mega_kernel(
    const float* x, const float* weight, const float* root_w,
    const float* root_b, float* out, unsigned short* wt,
    unsigned short* y, const int* ei, const int* et,
    int* counts, int* starts, int* cursor, int2* spill,
    unsigned* payload, int n_nodes, int n_edges, int nb, int nblk,
    int gemm_tiles, int ssh, int tsh)
{
    cg::grid_group grid = cg::this_grid();
    __shared__ __align__(16) char smem[57344];
    const int tid  = threadIdx.x;
    const int nthr = gridDim.x * FTHR;

    // ---------------- P1: prep W + zero spill cnt + chunk histograms -------
    for (int g = blockIdx.x * FTHR + tid; g < 5 * 4096; g += nthr) {
        int m = g >> 12, rem = g & 4095, c = rem >> 6, k = rem & 63;
        float v = (m < 4) ? weight[m * 4096 + k * 64 + c] : root_w[k * 64 + c];
        int byte = m * 8192 + c * 128 + ((k * 2) ^ ((c & 7) << 4));
        wt[byte >> 1] = f2bf(v);
    }
    if (blockIdx.x == 0 && tid == 0) cursor[nb] = 0;
    {
        int* lh = (int*)smem;
        for (int c = blockIdx.x; c < nblk; c += gridDim.x) {
            __syncthreads();
            for (int i = tid; i < nb; i += FTHR) lh[i] = 0;
            __syncthreads();
            const int lo = c * CHUNK;
            const int hi = min(lo + CHUNK, n_edges);
            for (int e = lo + tid; e < hi; e += FTHR)
                atomicAdd(&lh[ei[n_edges + e] >> 6], 1);
            __syncthreads();
            for (int i = tid; i < nb; i += FTHR)
                counts[(size_t)c * nb + i] = lh[i];
        }
    }
    grid.sync();

    // ---------------- P2: per-bucket scan across chunks (wave/bucket) ------
    {
        const int lane = tid & 63;
        for (int b = blockIdx.x * 8 + (tid >> 6); b < nb; b += gridDim.x * 8) {
            int base = 0;
            for (int r = 0; r * 64 < nblk; ++r) {
                int i = r * 64 + lane;
                int c = (i < nblk) ? counts[(size_t)i * nb + b] : 0;
                int s = c;
                #pragma unroll
                for (int d = 1; d < 64; d <<= 1) {
                    int u = __shfl_up(s, d, 64);
                    if (lane >= d) s += u;
                }
                if (i < nblk) starts[(size_t)i * nb + b] = base + s - c;
                base += __shfl(s, 63, 64);
            }
            if (lane == 0) cursor[b] = base;
        }
    }
    grid.sync();

    // ---------------- P3: fill items ∥ gemm items ---------------------------
    const int nit = nblk + gemm_tiles;
    for (int it = blockIdx.x; it < nit; it += gridDim.x) {
        __syncthreads();
        if (it < nblk) {
            // ------------------------- FILL item ---------------------------
            unsigned*       pl   = (unsigned*)smem;                 // 4096
            unsigned short* bkt  = (unsigned short*)(pl + CHUNK);   // 4096
            int*            lh   = (int*)(bkt + CHUNK);             // 1024
            int*            loff = lh + NBMAX1;                     // 1025
            int*            tsum = loff + NBMAX1 + 1;               // 512

            const int blk = it;
            const int lo  = blk * CHUNK;
            const int hi  = min(lo + CHUNK, n_edges);
            const int n   = hi - lo;

            for (int i = tid; i < nb; i += FTHR) lh[i] = 0;
            __syncthreads();
            for (int i = tid; i < n; i += FTHR)
                atomicAdd(&lh[ei[n_edges + lo + i] >> 6], 1);
            __syncthreads();

            const int bins  = (nb + FTHR - 1) / FTHR;
            const int base_ = tid * bins;
            int s = 0;
            for (int j = 0; j < bins; ++j) {
                int idx = base_ + j;
                if (idx < nb) s += lh[idx];
            }
            tsum[tid] = s;
            __syncthreads();
            for (int d = 1; d < FTHR; d <<= 1) {
                int v = (tid >= d) ? tsum[tid - d] : 0;
                __syncthreads();
                tsum[tid] += v;
                __syncthreads();
            }
            int run = (tid == 0) ? 0 : tsum[tid - 1];
            for (int j = 0; j < bins; ++j) {
                int idx = base_ + j;
                if (idx < nb) { loff[idx] = run; run += lh[idx]; }
            }
            __syncthreads();
            for (int i = tid; i < nb; i += FTHR) lh[i] = 0;
            __syncthreads();

            for (int i = tid; i < n; i += FTHR) {
                int e   = lo + i;
                int src = ei[e];
                int dn  = ei[n_edges + e];
                int t   = et[e];
                int b   = dn >> 6;
                int r   = atomicAdd(&lh[b], 1);
                int slot = loff[b] + r;
                pl[slot]  = (unsigned)src | ((unsigned)(dn & 63) << ssh)
                          | ((unsigned)t << tsh);
                bkt[slot] = (unsigned short)b;
            }
            __syncthreads();

            const int* srow = starts + (size_t)blk * nb;
            for (int i = tid; i < n; i += FTHR) {
                int b    = bkt[i];
                int rank = srow[b] + (i - loff[b]);
                unsigned v = pl[i];
                if (rank < CAPB) {
                    payload[(size_t)b * CAPB + rank] = v;
                } else {
                    int sp = atomicAdd(&cursor[nb], 1);
                    spill[sp] = make_int2(b, (int)v);
                }
            }
        } else {
            // ------------------------- GEMM item (128-node tile) -----------
            uint4* lds4 = (uint4*)smem;      // x [0,1024) ; Wt [1024,3584)
            const uint4* wt4 = (const uint4*)wt;
            const int node0 = (it - nblk) * 128;

            for (int i = tid; i < 2560; i += FTHR) lds4[1024 + i] = wt4[i];
            {
                int n    = tid >> 2;         // 0..127
                int kq   = tid & 3;
                int node = node0 + n;
                uint4 p0, p1;
                if (node < n_nodes) {
                    const float4* src = reinterpret_cast<const float4*>(x)
                                        + (size_t)node * 16 + kq * 4;
                    float4 f0 = src[0], f1 = src[1], f2 = src[2], f3 = src[3];
                    p0.x = pack2(f0.x, f0.y); p0.y = pack2(f0.z, f0.w);
                    p0.z = pack2(f1.x, f1.y); p0.w = pack2(f1.z, f1.w);
                    p1.x = pack2(f2.x, f2.y); p1.y = pack2(f2.z, f2.w);
                    p1.z = pack2(f3.x, f3.y); p1.w = pack2(f3.z, f3.w);
                } else {
                    p0 = make_uint4(0, 0, 0, 0);
                    p1 = p0;
                }
                int s0 = (kq * 2) ^ (n & 7);
                lds4[n * 8 + s0]       = p0;
                lds4[n * 8 + (s0 ^ 1)] = p1;
            }
            __syncthreads();

            const int wv = tid >> 6;
            const int l  = tid & 63;
            const int lo = l & 15;
            const int hi = l >> 4;

            const int arow = (wv >> 2) * 64 + (wv & 3) * 16 + lo;   // 0..127
            bf16x8 xb0 = *reinterpret_cast<const bf16x8*>(
                &lds4[arow * 8 + ((0 + hi) ^ (arow & 7))]);
            bf16x8 xb1 = *reinterpret_cast<const bf16x8*>(
                &lds4[arow * 8 + ((4 + hi) ^ (arow & 7))]);

            const int node   = node0 + arow;
            const bool valid = (node < n_nodes);

            for (int m = 0; m < 5; ++m) {
                f32x4 acc[4];
                #pragma unroll
                for (int j = 0; j < 4; ++j)
                    acc[j] = (f32x4){0.f, 0.f, 0.f, 0.f};
                #pragma unroll
                for (int j = 0; j < 4; ++j) {
                    int c     = j * 16 + lo;
                    int bbase = 1024 + m * 512 + c * 8;
                    bf16x8 w0 = *reinterpret_cast<const bf16x8*>(
                        &lds4[bbase + ((0 + hi) ^ (c & 7))]);
                    acc[j] = __builtin_amdgcn_mfma_f32_16x16x32_bf16(w0, xb0, acc[j], 0, 0, 0);
                    bf16x8 w1 = *reinterpret_cast<const bf16x8*>(
                        &lds4[bbase + ((4 + hi) ^ (c & 7))]);
                    acc[j] = __builtin_amdgcn_mfma_f32_16x16x32_bf16(w1, xb1, acc[j], 0, 0, 0);
                }
                if (m < 4) {
                    if (valid) {
                        unsigned short* ym = y + (size_t)m * n_nodes * 64;
                        #pragma unroll
                        for (int j = 0; j < 4; ++j) {
                            uint2 o;
                            o.x = pack2(acc[j][0], acc[j][1]);
                            o.y = pack2(acc[j][2], acc[j][3]);
                            *reinterpret_cast<uint2*>(
                                &ym[(size_t)node * 64 + j * 16 + hi * 4]) = o;
                        }
                    }
                } else {
                    if (valid) {
                        #pragma unroll
                        for (int j = 0; j < 4; ++j) {
                            float4 rb = reinterpret_cast<const float4*>(root_b)[j * 4 + hi];
                            float4 o  = make_float4(acc[j][0] + rb.x, acc[j][1] + rb.y,
                                                    acc[j][2] + rb.z, acc[j][3] + rb.w);
                            *reinterpret_cast<float4*>(
                                &out[(size_t)node * 64 + j * 16 + hi * 4]) = o;
                        }
                    }
                }
            }
        }
    }
    grid.sync();

    // ---------------- P4: gather (8 threads/node, 8 channels each) ----------
    for (int b = blockIdx.x; b < nb; b += gridDim.x) {
        __syncthreads();
        unsigned* raw  = (unsigned*)smem;        // CAPB
        unsigned* srt  = raw + CAPB;             // CAPB
        int*      hist = (int*)(srt + CAPB);     // 64
        int*      hoff = hist + 64;              // 65

        const int n_in = min(cursor[b], CAPB);
        const unsigned* pl_base = payload + (size_t)b * CAPB;

        if (tid < 64) hist[tid] = 0;
        __syncthreads();
        for (int i = tid; i < n_in; i += FTHR) {
            unsigned pl = pl_base[i];
            raw[i] = pl;
            atomicAdd(&hist[(pl >> ssh) & 63], 1);
        }
        __syncthreads();
        if (tid < 64) {
            int v = hist[tid];
            int s = v;
            #pragma unroll
            for (int d = 1; d < 64; d <<= 1) {
                int u = __shfl_up(s, d, 64);
                if (tid >= d) s += u;
            }
            hoff[tid] = s - v;
            if (tid == 63) hoff[64] = s;
            hist[tid] = 0;
        }
        __syncthreads();
        for (int i = tid; i < n_in; i += FTHR) {
            unsigned pl = raw[i];
            int lnode = (pl >> ssh) & 63;
            int r = atomicAdd(&hist[lnode], 1);
            srt[hoff[lnode] + r] = pl;
        }
        __syncthreads();

        const int g    = tid >> 3;            // node 0..63
        const int co   = (tid & 7) * 8;       // channel offset
        const int node = b * 64 + g;
        const unsigned smask = (1u << ssh) - 1;
        const uint4* y4 = reinterpret_cast<const uint4*>(y);

        float acc[8];
        #pragma unroll
        for (int j = 0; j < 8; ++j) acc[j] = 0.f;

        const int s0 = hoff[g];
        const int s1 = hoff[g + 1];
        int p = s0;
        for (; p + 1 < s1; p += 2) {
            unsigned pl0 = srt[p];
            unsigned pl1 = srt[p + 1];
            uint4 v0 = y4[(((size_t)(pl0 >> tsh) * n_nodes + (pl0 & smask)) * 64 + co) >> 3];
            uint4 v1 = y4[(((size_t)(pl1 >> tsh) * n_nodes + (pl1 & smask)) * 64 + co) >> 3];
            acc[0] += __builtin_bit_cast(float, v0.x << 16) + __builtin_bit_cast(float, v1.x << 16);
            acc[1] += __builtin_bit_cast(float, v0.x & 0xffff0000u) + __builtin_bit_cast(float, v1.x & 0xffff0000u);
            acc[2] += __builtin_bit_cast(float, v0.y << 16) + __builtin_bit_cast(float, v1.y << 16);
            acc[3] += __builtin_bit_cast(float, v0.y & 0xffff0000u) + __builtin_bit_cast(float, v1.y & 0xffff0000u);
            acc[4] += __builtin_bit_cast(float, v0.z << 16) + __builtin_bit_cast(float, v1.z << 16);
            acc[5] += __builtin_bit_cast(float, v0.z & 0xffff0000u) + __builtin_bit_cast(float, v1.z & 0xffff0000u);
            acc[6] += __builtin_bit_cast(float, v0.w << 16) + __builtin_bit_cast(float, v1.w << 16);
            acc[7] += __builtin_bit_cast(float, v0.w & 0xffff0000u) + __builtin_bit_cast(float, v1.w & 0xffff0000u);
        }
        if (p < s1) {
            unsigned pl = srt[p];
            uint4 v = y4[(((size_t)(pl >> tsh) * n_nodes + (pl & smask)) * 64 + co) >> 3];
            acc[0] += __builtin_bit_cast(float, v.x << 16);
            acc[1] += __builtin_bit_cast(float, v.x & 0xffff0000u);
            acc[2] += __builtin_bit_cast(float, v.y << 16);
            acc[3] += __builtin_bit_cast(float, v.y & 0xffff0000u);
            acc[4] += __builtin_bit_cast(float, v.z << 16);
            acc[5] += __builtin_bit_cast(float, v.z & 0xffff0000u);
            acc[6] += __builtin_bit_cast(float, v.w << 16);
            acc[7] += __builtin_bit_cast(float, v.w & 0xffff0000u);
        }

        const int S = cursor[nb];             // spill drain (normally 0)
        for (int i = 0; i < S; ++i) {
            int2 sp = spill[i];
            if (sp.x == b) {
                unsigned v = (unsigned)sp.y;
                if ((int)((v >> ssh) & 63) == g) {
                    int src = (int)(v & smask);
                    int t   = (int)(v >> tsh);
                    const unsigned short* yr = y + ((size_t)t * n_nodes + src) * 64 + co;
                    #pragma unroll
                    for (int j = 0; j < 8; ++j) acc[j] += bf2f(yr[j]);
                }
            }
        }

        if (node < n_nodes) {
            float4* o = reinterpret_cast<float4*>(out + (size_t)node * 64 + co);
            float4 a = o[0], c2 = o[1];
            a.x += acc[0]; a.y += acc[1]; a.z += acc[2]; a.w += acc[3];
            c2.x += acc[4]; c2.y += acc[5]; c2.z += acc[6]; c2.w += acc[7];
            o[0] = a; o[1] = c2;
        }
    }
}

// ================= fallback chain (R15, non-cooperative) ====================
__global__ __launch_bounds__(FTHR) void ph_kernel(
    const float* __restrict__ weight, const float* __restrict__ root_w,
    unsigned short* __restrict__ wt,
    const int* __restrict__ ei, int* __restrict__ counts,
    int n_edges, int nb, int nblk)
{
    const int tid = threadIdx.x;
    int g = blockIdx.x * FTHR + tid;
    if (g < 5 * 4096) {
        int m = g >> 12, rem = g & 4095, c = rem >> 6, k = rem & 63;
        float v = (m < 4) ? weight[m * 4096 + k * 64 + c] : root_w[k * 64 + c];
        int byte = m * 8192 + c * 128 + ((k * 2) ^ ((c & 7) << 4));
        wt[byte >> 1] = f2bf(v);
    }
    if (blockIdx.x >= nblk) return;
    __shared__ int lh[NBMAX1];
    for (int i = tid; i < nb; i += FTHR) lh[i] = 0;
    __syncthreads();
    const int lo = blockIdx.x * CHUNK;
    const int hi = min(lo + CHUNK, n_edges);
    for (int e = lo + tid; e < hi; e += FTHR)
        atomicAdd(&lh[ei[n_edges + e] >> 6], 1);
    __syncthreads();
    for (int i = tid; i < nb; i += FTHR)
        counts[(size_t)blockIdx.x * nb + i] = lh[i];
}

__global__ __launch_bounds__(256) void scanw_kernel(
    const int* __restrict__ counts, int* __restrict__ starts,
    int* __restrict__ cursor, int nb, int nblk)
{
    if (blockIdx.x == 0 && threadIdx.x == 0) cursor[nb] = 0;
    const int w    = (blockIdx.x * 256 + threadIdx.x) >> 6;
    const int lane = threadIdx.x & 63;
    if (w >= nb) return;
    const int b = w;
    int base = 0;
    for (int r = 0; r * 64 < nblk; ++r) {
        int i = r * 64 + lane;
        int c = (i < nblk) ? counts[(size_t)i * nb + b] : 0;
        int s = c;
        #pragma unroll
        for (int d = 1; d < 64; d <<= 1) {
            int u = __shfl_up(s, d, 64);
            if (lane >= d) s += u;
        }
        if (i < nblk) starts[(size_t)i * nb + b] = base + s - c;
        base += __shfl(s, 63, 64);
    }
    if (lane == 0) cursor[b] = base;
}

__global__ __launch_bounds__(FTHR) void fused_fg_kernel(
    const float* __restrict__ x, const uint4* __restrict__ wt4,
    const float* __restrict__ root_b,
    float* __restrict__ out, unsigned short* __restrict__ y, int n_nodes,
    const int* __restrict__ ei, const int* __restrict__ et,
    const int* __restrict__ starts, int* __restrict__ cursor,
    int2* __restrict__ spill, unsigned* __restrict__ payload,
    int n_edges, int nb, int nblk, int ssh, int tsh)
{
    __shared__ __align__(16) char smem[57344];
    const int tid = threadIdx.x;
    if (blockIdx.x < nblk) {
        unsigned*       pl   = (unsigned*)smem;
        unsigned short* bkt  = (unsigned short*)(pl + CHUNK);
        int*            lh   = (int*)(bkt + CHUNK);
        int*            loff = lh + NBMAX1;
        int*            tsum = loff + NBMAX1 + 1;
        const int blk = blockIdx.x;
        const int lo  = blk * CHUNK;
        const int hi  = min(lo + CHUNK, n_edges);
        const int n   = hi - lo;
        for (int i = tid; i < nb; i += FTHR) lh[i] = 0;
        __syncthreads();
        for (int i = tid; i < n; i += FTHR)
            atomicAdd(&lh[ei[n_edges + lo + i] >> 6], 1);
        __syncthreads();
        const int bins  = (nb + FTHR - 1) / FTHR;
        const int base_ = tid * bins;
        int s = 0;
        for (int j = 0; j < bins; ++j) {
            int idx = base_ + j;
            if (idx < nb) s += lh[idx];
        }
        tsum[tid] = s;
        __syncthreads();
        for (int d = 1; d < FTHR; d <<= 1) {
            int v = (tid >= d) ? tsum[tid - d] : 0;
            __syncthreads();
            tsum[tid] += v;
            __syncthreads();
        }
        int run = (tid == 0) ? 0 : tsum[tid - 1];
        for (int j = 0; j < bins; ++j) {
            int idx = base_ + j;
            if (idx < nb) { loff[idx] = run; run += lh[idx]; }
        }
        __syncthreads();
        for (int i = tid; i < nb; i += FTHR) lh[i] = 0;
        __syncthreads();
        for (int i = tid; i < n; i += FTHR) {
            int e   = lo + i;
            int src = ei[e];
            int dn  = ei[n_edges + e];
            int t   = et[e];
            int b   = dn >> 6;
            int r   = atomicAdd(&lh[b], 1);
            int slot = loff[b] + r;
            pl[slot]  = (unsigned)src | ((unsigned)(dn & 63) << ssh)
                      | ((unsigned)t << tsh);
            bkt[slot] = (unsigned short)b;
        }
        __syncthreads();
        const int* __restrict__ srow = starts + (size_t)blk * nb;
        for (int i = tid; i < n; i += FTHR) {
            int b    = bkt[i];
            int rank = srow[b] + (i - loff[b]);
            unsigned v = pl[i];
            if (rank < CAPB) payload[(size_t)b * CAPB + rank] = v;
            else { int sp = atomicAdd(&cursor[nb], 1); spill[sp] = make_int2(b, (int)v); }
        }
        return;
    }
    uint4* lds4 = (uint4*)smem;
    const int node0 = (blockIdx.x - nblk) * 128;
    for (int i = tid; i < 2560; i += FTHR) lds4[1024 + i] = wt4[i];
    {
        int n    = tid >> 2;
        int kq   = tid & 3;
        int node = node0 + n;
        uint4 p0, p1;
        if (node < n_nodes) {
            const float4* src = reinterpret_cast<const float4*>(x)
                                + (size_t)node * 16 + kq * 4;
            float4 f0 = src[0], f1 = src[1], f2 = src[2], f3 = src[3];
            p0.x = pack2(f0.x, f0.y); p0.y = pack2(f0.z, f0.w);
            p0.z = pack2(f1.x, f1.y); p0.w = pack2(f1.z, f1.w);
            p1.x = pack2(f2.x, f2.y); p1.y = pack2(f2.z, f2.w);
            p1.z = pack2(f3.x, f3.y); p1.w = pack2(f3.z, f3.w);
        } else { p0 = make_uint4(0, 0, 0, 0); p1 = p0; }
        int s0 = (kq * 2) ^ (n & 7);
        lds4[n * 8 + s0]       = p0;
        lds4[n * 8 + (s0 ^ 1)] = p1;
    }
    __syncthreads();
    const int wv = tid >> 6;
    const int l  = tid & 63;
    const int lo = l & 15;
    const int hi = l >> 4;
    const int arow = (wv >> 2) * 64 + (wv & 3) * 16 + lo;
    bf16x8 xb0 = *reinterpret_cast<const bf16x8*>(
        &lds4[arow * 8 + ((0 + hi) ^ (arow & 7))]);
    bf16x8 xb1 = *reinterpret_cast<const bf16x8*>(
        &lds4[arow * 8 + ((4 + hi) ^ (arow & 7))]);
    const int node   = node0 + arow;
    const bool valid = (node < n_nodes);
    for (int m = 0; m < 5; ++m) {
        f32x4 acc[4];
        #pragma unroll
        for (int j = 0; j < 4; ++j) acc[j] = (f32x4){0.f, 0.f, 0.f, 0.f};
        #pragma unroll
        for (int j = 0; j < 4; ++j) {
            int c     = j * 16 + lo;
            int bbase = 1024 + m * 512 + c * 8;
            bf16x8 w0 = *reinterpret_cast<const bf16x8*>(
                &lds4[bbase + ((0 + hi) ^ (c & 7))]);
            acc[j] = __builtin_amdgcn_mfma_f32_16x16x32_bf16(w0, xb0, acc[j], 0, 0, 0);
            bf16x8 w1 = *reinterpret_cast<const bf16x8*>(
                &lds4[bbase + ((4 + hi) ^ (c & 7))]);
            acc[j] = __builtin_amdgcn_mfma_f32_16x16x32_bf16(w1, xb1, acc[j], 0, 0, 0);
        }
        if (m < 4) {
            if (valid) {
                unsigned short* __restrict__ ym = y + (size_t)m * n_nodes * 64;
                #pragma unroll
                for (int j = 0; j < 4; ++j) {
                    uint2 o;
                    o.x = pack2(acc[j][0], acc[j][1]);
                    o.y = pack2(acc[j][2], acc[j][3]);
                    *reinterpret_cast<uint2*>(
                        &ym[(size_t)node * 64 + j * 16 + hi * 4]) = o;
                }
            }
        } else if (valid) {
            #pragma unroll
            for (int j = 0; j < 4; ++j) {
                float4 rb = reinterpret_cast<const float4*>(root_b)[j * 4 + hi];
                float4 o  = make_float4(acc[j][0] + rb.x, acc[j][1] + rb.y,
                                        acc[j][2] + rb.z, acc[j][3] + rb.w);
                *reinterpret_cast<float4*>(
                    &out[(size_t)node * 64 + j * 16 + hi * 4]) = o;
            }
        }
    }
}

__global__ __launch_bounds__(1024) void gatherb5_kernel(
    const int* __restrict__ cursor, const unsigned* __restrict__ payload,
    const int2* __restrict__ spill,
    const unsigned short* __restrict__ y, float* __restrict__ out,
    int n_nodes, int nb, int ssh, int tsh)
{
    __shared__ unsigned raw[CAPB];
    __shared__ unsigned srt[CAPB];
    __shared__ int hist[64];
    __shared__ int hoff[65];
    const int tid = threadIdx.x;
    const int b   = blockIdx.x;
    const int n_in = min(cursor[b], CAPB);
    const unsigned* __restrict__ pl_base = payload + (size_t)b * CAPB;
    if (tid < 64) hist[tid] = 0;
    __syncthreads();
    for (int i = tid; i < n_in; i += 1024) {
        unsigned pl = pl_base[i];
        raw[i] = pl;
        atomicAdd(&hist[(pl >> ssh) & 63], 1);
    }
    __syncthreads();
    if (tid < 64) {
        int v = hist[tid];
        int s = v;
        #pragma unroll
        for (int d = 1; d < 64; d <<= 1) {
            int u = __shfl_up(s, d, 64);
            if (tid >= d) s += u;
        }
        hoff[tid] = s - v;
        if (tid == 63) hoff[64] = s;
        hist[tid] = 0;
    }
    __syncthreads();
    for (int i = tid; i < n_in; i += 1024) {
        unsigned pl = raw[i];
        int lnode = (pl >> ssh) & 63;
        int r = atomicAdd(&hist[lnode], 1);
        srt[hoff[lnode] + r] = pl;
    }
    __syncthreads();
    const int g    = tid >> 4;
    const int cq   = tid & 15;
    const int node = b * 64 + g;
    const unsigned smask = (1u << ssh) - 1;
    const ushort4* __restrict__ y4 = reinterpret_cast<const ushort4*>(y);
    float4 acc = make_float4(0.f, 0.f, 0.f, 0.f);
    const int s0 = hoff[g];
    const int s1 = hoff[g + 1];
    int p = s0;
    for (; p + 1 < s1; p += 2) {
        unsigned pl0 = srt[p];
        unsigned pl1 = srt[p + 1];
        ushort4 v0 = y4[((long)(pl0 >> tsh) * n_nodes + (pl0 & smask)) * 16 + cq];
        ushort4 v1 = y4[((long)(pl1 >> tsh) * n_nodes + (pl1 & smask)) * 16 + cq];
        acc.x += bf2f(v0.x) + bf2f(v1.x);
        acc.y += bf2f(v0.y) + bf2f(v1.y);
        acc.z += bf2f(v0.z) + bf2f(v1.z);
        acc.w += bf2f(v0.w) + bf2f(v1.w);
    }
    if (p < s1) {
        unsigned pl = srt[p];
        ushort4 v = y4[((long)(pl >> tsh) * n_nodes + (pl & smask)) * 16 + cq];
        acc.x += bf2f(v.x); acc.y += bf2f(v.y);
        acc.z += bf2f(v.z); acc.w += bf2f(v.w);
    }
    const int S = cursor[nb];
    for (int i = 0; i < S; ++i) {
        int2 sp = spill[i];
        if (sp.x == b) {
            unsigned v = (unsigned)sp.y;
            if ((int)((v >> ssh) & 63) == g) {
                int src = (int)(v & smask);
                int t   = (int)(v >> tsh);
                ushort4 w = y4[((long)t * n_nodes + src) * 16 + cq];
                acc.x += bf2f(w.x); acc.y += bf2f(w.y);
                acc.z += bf2f(w.z); acc.w += bf2f(w.w);
            }
        }
    }
    if (node < n_nodes) {
        float4* o  = reinterpret_cast<float4*>(out) + (long)node * 16 + cq;
        float4 cur = *o;
        cur.x += acc.x; cur.y += acc.y; cur.z += acc.z; cur.w += acc.w;
        *o = cur;
    }
}

// -------------------- minimal safety fallbacks ------------------------------
__global__ __launch_bounds__(256) void gemm_root_kernel(
    const float* __restrict__ x, const float* __restrict__ root_w,
    const float* __restrict__ root_b, float* __restrict__ out, int n_nodes)
{
    __shared__ float xs[NT][65];
    __shared__ float ws[64][65];
    const int tid   = threadIdx.x;
    const int node0 = blockIdx.x * NT;
    #pragma unroll
    for (int i = 0; i < 4; ++i) {
        int v  = tid + i * 256;
        int r  = v >> 4;
        int cq = v & 15;
        float4 w4 = reinterpret_cast<const float4*>(root_w)[v];
        ws[r][cq * 4 + 0] = w4.x; ws[r][cq * 4 + 1] = w4.y;
        ws[r][cq * 4 + 2] = w4.z; ws[r][cq * 4 + 3] = w4.w;
        int node = node0 + r;
        float4 x4 = (node < n_nodes)
                        ? reinterpret_cast<const float4*>(x)[node * 16 + cq]
                        : make_float4(0.f, 0.f, 0.f, 0.f);
        xs[r][cq * 4 + 0] = x4.x; xs[r][cq * 4 + 1] = x4.y;
        xs[r][cq * 4 + 2] = x4.z; xs[r][cq * 4 + 3] = x4.w;
    }
    __syncthreads();
    const int tc = (tid & 15) * 4;
    const int tr = (tid >> 4) * 4;
    float acc[4][4];
    #pragma unroll
    for (int i = 0; i < 4; ++i)
        #pragma unroll
        for (int j = 0; j < 4; ++j) acc[i][j] = 0.f;
    #pragma unroll 4
    for (int k = 0; k < 64; ++k) {
        float xv[4], wv[4];
        #pragma unroll
        for (int i = 0; i < 4; ++i) xv[i] = xs[tr + i][k];
        #pragma unroll
        for (int j = 0; j < 4; ++j) wv[j] = ws[k][tc + j];
        #pragma unroll
        for (int i = 0; i < 4; ++i)
            #pragma unroll
            for (int j = 0; j < 4; ++j) acc[i][j] += xv[i] * wv[j];
    }
    #pragma unroll
    for (int i = 0; i < 4; ++i) {
        int node = node0 + tr + i;
        if (node < n_nodes) {
            float4 o = make_float4(acc[i][0] + root_b[tc + 0], acc[i][1] + root_b[tc + 1],
                                   acc[i][2] + root_b[tc + 2], acc[i][3] + root_b[tc + 3]);
            reinterpret_cast<float4*>(out)[node * 16 + (tc >> 2)] = o;
        }
    }
}

__global__ __launch_bounds__(256) void edge_direct_kernel(
    const float* __restrict__ x, const int* __restrict__ ei,
    const int* __restrict__ et, const float* __restrict__ weight,
    float* __restrict__ out, int n_edges)
{
    int gwave  = (int)((blockIdx.x * (long)blockDim.x + threadIdx.x) >> 6);
    int lane   = threadIdx.x & 63;
    int nwaves = (int)(((long)gridDim.x * blockDim.x) >> 6);
    for (int e = gwave; e < n_edges; e += nwaves) {
        int src  = ei[e];
        int dstn = ei[n_edges + e];
        int t    = et[e];
        float xv = x[src * 64 + lane];
        const float* __restrict__ W = weight + t * 4096;
        float acc = 0.f;
        #pragma unroll 8
        for (int k = 0; k < 64; ++k) {
            float xk = __shfl(xv, k);
            acc += xk * W[k * 64 + lane];
        }
        atomicAdd(&out[(long)dstn * 64 + lane], acc);
    }
}

extern "C" void kernel_launch(void* const* d_in, const int* in_sizes, int n_in,
                              void* d_out, int out_size, void* d_ws, size_t ws_size,
                              hipStream_t stream) {
    const float* x      = (const float*)d_in[0];
    const int*   ei     = (const int*)d_in[1];   // [2, E] int32
    const int*   et     = (const int*)d_in[2];   // [E]
    const float* weight = (const float*)d_in[3]; // [4, 64, 64]
    const float* root_w = (const float*)d_in[4]; // [64, 64]
    const float* root_b = (const float*)d_in[5]; // [64]
    float* out = (float*)d_out;

    const int n_nodes = in_sizes[0] / 64;
    const int n_edges = in_sizes[2];
    const int nb      = (n_nodes + 63) >> 6;
    const int nblk    = (n_edges + CHUNK - 1) / CHUNK;
    const int gemm_tiles = (n_nodes + 127) / 128;

    int ssh = 1;
    while ((1 << ssh) < n_nodes) ++ssh;   // bits for src
    const int tsh = ssh + 6;              // 6 bits for local dst

    const size_t wt_bytes = 5 * 4096 * sizeof(unsigned short);   // 40 KB
    const size_t y_bytes  = (size_t)4 * n_nodes * 64 * sizeof(unsigned short);
    const size_t b_bytes  = wt_bytes + y_bytes +
        ((size_t)nb + 1 + 2 * (size_t)nblk * nb + (size_t)nb * CAPB
         + 2 * (size_t)n_edges) * 4;

    if (nb <= NBMAX1 && tsh + 2 <= 32 && ws_size >= b_bytes) {
        unsigned short* wt      = (unsigned short*)d_ws;
        unsigned short* y       = (unsigned short*)((char*)d_ws + wt_bytes);
        int*            cursor  = (int*)((char*)d_ws + wt_bytes + y_bytes);
        int*            counts  = cursor + nb + 1;
        int*            starts  = counts + (size_t)nblk * nb;
        unsigned*       payload = (unsigned*)(starts + (size_t)nblk * nb);
        int2*           spill   = (int2*)(payload + (size_t)nb * CAPB);

        int coop = 0, maxb = 0, ncu = 0, dev = 0;
        hipGetDevice(&dev);
        hipDeviceGetAttribute(&coop, hipDeviceAttributeCooperativeLaunch, dev);
        hipDeviceGetAttribute(&ncu, hipDeviceAttributeMultiprocessorCount, dev);
        hipOccupancyMaxActiveBlocksPerMultiprocessor(&maxb, mega_kernel, FTHR, 0);

        if (coop && maxb > 0 && ncu > 0) {
            int grid = maxb * ncu;
            if (grid > 512) grid = 512;
            void* args[] = {
                (void*)&x, (void*)&weight, (void*)&root_w, (void*)&root_b,
                (void*)&out, (void*)&wt, (void*)&y, (void*)&ei, (void*)&et,
                (void*)&counts, (void*)&starts, (void*)&cursor, (void*)&spill,
                (void*)&payload, (void*)&n_nodes, (void*)&n_edges, (void*)&nb,
                (void*)&nblk, (void*)&gemm_tiles, (void*)&ssh, (void*)&tsh };
            hipLaunchCooperativeKernel((const void*)mega_kernel, dim3(grid),
                                       dim3(FTHR), args, 0, stream);
        } else {
            const int ph_blocks = max(nblk, (5 * 4096 + FTHR - 1) / FTHR);
            ph_kernel<<<ph_blocks, FTHR, 0, stream>>>(
                weight, root_w, wt, ei, counts, n_edges, nb, nblk);
            scanw_kernel<<<(nb * 64 + 255) / 256, 256, 0, stream>>>(
                counts, starts, cursor, nb, nblk);
            fused_fg_kernel<<<nblk + gemm_tiles, FTHR, 0, stream>>>(
                x, (const uint4*)wt, root_b, out, y, n_nodes,
                ei, et, starts, cursor, spill, payload,
                n_edges, nb, nblk, ssh, tsh);
            gatherb5_kernel<<<nb, 1024, 0, stream>>>(
                cursor, payload, spill, y, out, n_nodes, nb, ssh, tsh);
        }
    } else {
        gemm_root_kernel<<<(n_nodes + NT - 1) / NT, 256, 0, stream>>>(
            x, root_w, root_b, out, n_nodes);
        edge_direct_kernel<<<4096, 256, 0, stream>>>(x, ei, et, weight, out, n_edges);
    }
}

// Round 17
// 64.327 us; speedup vs baseline: 2.8007x; 2.8007x over previous
//
#include <hip/hip_runtime.h>

#define NT 64
#define NBMAX1 1024   // max buckets for the fast path (nodes <= 65536)
#define CAPB 2048     // payload slots per bucket (mean ~1279 here)
#define CHUNK 4096    // edges per fill block
#define FTHR 512      // threads for fast-path kernels

typedef short bf16x8 __attribute__((ext_vector_type(8)));
typedef float f32x4  __attribute__((ext_vector_type(4)));

__device__ __forceinline__ unsigned short f2bf(float f) {
    unsigned u = __builtin_bit_cast(unsigned, f);
    unsigned r = (u + 0x7fffu + ((u >> 16) & 1u)) >> 16;   // round-nearest-even
    return (unsigned short)r;
}
__device__ __forceinline__ float bf2f(unsigned short h) {
    return __builtin_bit_cast(float, (unsigned)h << 16);
}
__device__ __forceinline__ unsigned pack2(float a, float b) {
    return (unsigned)f2bf(a) | ((unsigned)f2bf(b) << 16);
}

// ---------------------------------------------------------------------------
// ph: prep W (bf16, transposed [m][col][k], XOR-swizzled) on the first
// 20480 threads, AND per-chunk LDS histogram -> counts[blk*nb+b]
// (blocks < nblk). Zero global atomics.
// ---------------------------------------------------------------------------
__global__ __launch_bounds__(FTHR) void ph_kernel(
    const float* __restrict__ weight, const float* __restrict__ root_w,
    unsigned short* __restrict__ wt,
    const int* __restrict__ ei, int* __restrict__ counts,
    int n_edges, int nb, int nblk)
{
    const int tid = threadIdx.x;
    int g = blockIdx.x * FTHR + tid;
    if (g < 5 * 4096) {
        int m = g >> 12, rem = g & 4095, c = rem >> 6, k = rem & 63;
        float v = (m < 4) ? weight[m * 4096 + k * 64 + c] : root_w[k * 64 + c];
        int byte = m * 8192 + c * 128 + ((k * 2) ^ ((c & 7) << 4));
        wt[byte >> 1] = f2bf(v);
    }
    if (blockIdx.x >= nblk) return;

    __shared__ int lh[NBMAX1];
    for (int i = tid; i < nb; i += FTHR) lh[i] = 0;
    __syncthreads();
    const int lo = blockIdx.x * CHUNK;
    const int hi = min(lo + CHUNK, n_edges);
    for (int e = lo + tid; e < hi; e += FTHR)
        atomicAdd(&lh[ei[n_edges + e] >> 6], 1);
    __syncthreads();
    for (int i = tid; i < nb; i += FTHR)
        counts[(size_t)blockIdx.x * nb + i] = lh[i];
}

// ---------------------------------------------------------------------------
// scanw: ONE WAVE PER BUCKET. shfl-scan across nblk chunks (rounds of 64).
// Writes starts[blk*nb+b] (exclusive prefix) and cursor[b] (total).
// cursor[nb] (spill count) zeroed here.
// ---------------------------------------------------------------------------
__global__ __launch_bounds__(256) void scanw_kernel(
    const int* __restrict__ counts, int* __restrict__ starts,
    int* __restrict__ cursor, int nb, int nblk)
{
    if (blockIdx.x == 0 && threadIdx.x == 0) cursor[nb] = 0;
    const int w    = (blockIdx.x * 256 + threadIdx.x) >> 6;
    const int lane = threadIdx.x & 63;
    if (w >= nb) return;
    const int b = w;
    int base = 0;
    for (int r = 0; r * 64 < nblk; ++r) {
        int i = r * 64 + lane;
        int c = (i < nblk) ? counts[(size_t)i * nb + b] : 0;
        int s = c;
        #pragma unroll
        for (int d = 1; d < 64; d <<= 1) {
            int u = __shfl_up(s, d, 64);
            if (lane >= d) s += u;
        }
        if (i < nblk) starts[(size_t)i * nb + b] = base + s - c;
        base += __shfl(s, 63, 64);
    }
    if (lane == 0) cursor[b] = base;
}

// ---------------------------------------------------------------------------
// Fused fillC ∥ gemm (FTHR=512 threads).
//  blocks [0,nblk): counting-sort chunk in LDS (bkt[] recorded -> direct
//  lookup, no binary search), write contiguous runs at deterministic
//  positions. No global atomics (spill only on overflow, never here).
//  blocks [nblk, ...): MFMA GEMM, 128-node tile, 8 waves.
// payload = src | ldst<<ssh | type<<tsh
// ---------------------------------------------------------------------------
__global__ __launch_bounds__(FTHR) void fused_fg_kernel(
    const float* __restrict__ x, const uint4* __restrict__ wt4,
    const float* __restrict__ root_b,
    float* __restrict__ out, unsigned short* __restrict__ y, int n_nodes,
    const int* __restrict__ ei, const int* __restrict__ et,
    const int* __restrict__ starts, int* __restrict__ cursor,
    int2* __restrict__ spill, unsigned* __restrict__ payload,
    int n_edges, int nb, int nblk, int ssh, int tsh)
{
    __shared__ __align__(16) char smem[57344];   // 56 KB
    const int tid = threadIdx.x;

    if (blockIdx.x < nblk) {
        // ------------------------- FILL path -------------------------------
        unsigned*       pl   = (unsigned*)smem;                    // CHUNK
        unsigned short* bkt  = (unsigned short*)(pl + CHUNK);      // CHUNK
        int*            lh   = (int*)(bkt + CHUNK);                // NBMAX1
        int*            loff = lh + NBMAX1;                        // NBMAX1+1
        int*            tsum = loff + NBMAX1 + 1;                  // FTHR

        const int blk = blockIdx.x;
        const int lo  = blk * CHUNK;
        const int hi  = min(lo + CHUNK, n_edges);
        const int n   = hi - lo;

        for (int i = tid; i < nb; i += FTHR) lh[i] = 0;
        __syncthreads();
        for (int i = tid; i < n; i += FTHR)
            atomicAdd(&lh[ei[n_edges + lo + i] >> 6], 1);
        __syncthreads();

        // exclusive scan lh[0..nb) -> loff
        const int bins  = (nb + FTHR - 1) / FTHR;
        const int base_ = tid * bins;
        int s = 0;
        for (int j = 0; j < bins; ++j) {
            int idx = base_ + j;
            if (idx < nb) s += lh[idx];
        }
        tsum[tid] = s;
        __syncthreads();
        for (int d = 1; d < FTHR; d <<= 1) {
            int v = (tid >= d) ? tsum[tid - d] : 0;
            __syncthreads();
            tsum[tid] += v;
            __syncthreads();
        }
        int run = (tid == 0) ? 0 : tsum[tid - 1];
        for (int j = 0; j < bins; ++j) {
            int idx = base_ + j;
            if (idx < nb) { loff[idx] = run; run += lh[idx]; }
        }
        __syncthreads();
        for (int i = tid; i < nb; i += FTHR) lh[i] = 0;
        __syncthreads();

        // ranked placement into LDS; record bucket per slot
        for (int i = tid; i < n; i += FTHR) {
            int e   = lo + i;
            int src = ei[e];
            int dn  = ei[n_edges + e];
            int t   = et[e];
            int b   = dn >> 6;
            int r   = atomicAdd(&lh[b], 1);
            int slot = loff[b] + r;
            pl[slot]  = (unsigned)src | ((unsigned)(dn & 63) << ssh)
                      | ((unsigned)t << tsh);
            bkt[slot] = (unsigned short)b;
        }
        __syncthreads();

        // write out: direct bucket lookup; consecutive slots -> consecutive
        // payload addresses within each run.
        const int* __restrict__ srow = starts + (size_t)blk * nb;
        for (int i = tid; i < n; i += FTHR) {
            int b    = bkt[i];
            int rank = srow[b] + (i - loff[b]);
            unsigned v = pl[i];
            if (rank < CAPB) {
                payload[(size_t)b * CAPB + rank] = v;
            } else {
                int sp = atomicAdd(&cursor[nb], 1);
                spill[sp] = make_int2(b, (int)v);
            }
        }
        return;
    }

    // --------------------------- GEMM path (128-node tile) -----------------
    uint4* lds4 = (uint4*)smem;          // x: [0,1024) ; Wt: [1024,3584)
    const int node0 = (blockIdx.x - nblk) * 128;

    for (int i = tid; i < 2560; i += FTHR) lds4[1024 + i] = wt4[i];

    {
        int n    = tid >> 2;             // 0..127
        int kq   = tid & 3;
        int node = node0 + n;
        uint4 p0, p1;
        if (node < n_nodes) {
            const float4* src = reinterpret_cast<const float4*>(x)
                                + (size_t)node * 16 + kq * 4;
            float4 f0 = src[0], f1 = src[1], f2 = src[2], f3 = src[3];
            p0.x = pack2(f0.x, f0.y); p0.y = pack2(f0.z, f0.w);
            p0.z = pack2(f1.x, f1.y); p0.w = pack2(f1.z, f1.w);
            p1.x = pack2(f2.x, f2.y); p1.y = pack2(f2.z, f2.w);
            p1.z = pack2(f3.x, f3.y); p1.w = pack2(f3.z, f3.w);
        } else {
            p0 = make_uint4(0, 0, 0, 0);
            p1 = p0;
        }
        int s0 = (kq * 2) ^ (n & 7);
        lds4[n * 8 + s0]       = p0;
        lds4[n * 8 + (s0 ^ 1)] = p1;
    }
    __syncthreads();

    const int wv = tid >> 6;             // 0..7
    const int l  = tid & 63;
    const int lo = l & 15;
    const int hi = l >> 4;

    const int arow = (wv >> 2) * 64 + (wv & 3) * 16 + lo;   // 0..127
    bf16x8 xb0 = *reinterpret_cast<const bf16x8*>(
        &lds4[arow * 8 + ((0 + hi) ^ (arow & 7))]);
    bf16x8 xb1 = *reinterpret_cast<const bf16x8*>(
        &lds4[arow * 8 + ((4 + hi) ^ (arow & 7))]);

    const int node   = node0 + arow;
    const bool valid = (node < n_nodes);

    for (int m = 0; m < 5; ++m) {
        f32x4 acc[4];
        #pragma unroll
        for (int j = 0; j < 4; ++j)
            acc[j] = (f32x4){0.f, 0.f, 0.f, 0.f};

        #pragma unroll
        for (int j = 0; j < 4; ++j) {
            int c     = j * 16 + lo;
            int bbase = 1024 + m * 512 + c * 8;
            bf16x8 w0 = *reinterpret_cast<const bf16x8*>(
                &lds4[bbase + ((0 + hi) ^ (c & 7))]);
            acc[j] = __builtin_amdgcn_mfma_f32_16x16x32_bf16(w0, xb0, acc[j], 0, 0, 0);
            bf16x8 w1 = *reinterpret_cast<const bf16x8*>(
                &lds4[bbase + ((4 + hi) ^ (c & 7))]);
            acc[j] = __builtin_amdgcn_mfma_f32_16x16x32_bf16(w1, xb1, acc[j], 0, 0, 0);
        }

        if (m < 4) {
            if (valid) {
                unsigned short* __restrict__ ym = y + (size_t)m * n_nodes * 64;
                #pragma unroll
                for (int j = 0; j < 4; ++j) {
                    uint2 o;
                    o.x = pack2(acc[j][0], acc[j][1]);
                    o.y = pack2(acc[j][2], acc[j][3]);
                    *reinterpret_cast<uint2*>(
                        &ym[(size_t)node * 64 + j * 16 + hi * 4]) = o;
                }
            }
        } else {
            if (valid) {
                #pragma unroll
                for (int j = 0; j < 4; ++j) {
                    float4 rb = reinterpret_cast<const float4*>(root_b)[j * 4 + hi];
                    float4 o  = make_float4(acc[j][0] + rb.x, acc[j][1] + rb.y,
                                            acc[j][2] + rb.z, acc[j][3] + rb.w);
                    *reinterpret_cast<float4*>(
                        &out[(size_t)node * 64 + j * 16 + hi * 4]) = o;
                }
            }
        }
    }
}

// ---------------------------------------------------------------------------
// Gather: one 1024-thread block per bucket; in-LDS counting sort by local dst,
// 64 groups x 16 threads accumulate in registers (unroll x4). int2 spill.
// ---------------------------------------------------------------------------
__global__ __launch_bounds__(1024) void gatherb5_kernel(
    const int* __restrict__ cursor, const unsigned* __restrict__ payload,
    const int2* __restrict__ spill,
    const unsigned short* __restrict__ y, float* __restrict__ out,
    int n_nodes, int nb, int ssh, int tsh)
{
    __shared__ unsigned raw[CAPB];
    __shared__ unsigned srt[CAPB];
    __shared__ int hist[64];
    __shared__ int hoff[65];

    const int tid = threadIdx.x;
    const int b   = blockIdx.x;
    const int n_in = min(cursor[b], CAPB);
    const unsigned* __restrict__ pl_base = payload + (size_t)b * CAPB;

    if (tid < 64) hist[tid] = 0;
    __syncthreads();
    for (int i = tid; i < n_in; i += 1024) {
        unsigned pl = pl_base[i];
        raw[i] = pl;
        atomicAdd(&hist[(pl >> ssh) & 63], 1);
    }
    __syncthreads();
    if (tid < 64) {                       // wave-parallel exclusive scan
        int v = hist[tid];
        int s = v;
        #pragma unroll
        for (int d = 1; d < 64; d <<= 1) {
            int u = __shfl_up(s, d, 64);
            if (tid >= d) s += u;
        }
        hoff[tid] = s - v;
        if (tid == 63) hoff[64] = s;
        hist[tid] = 0;
    }
    __syncthreads();
    for (int i = tid; i < n_in; i += 1024) {
        unsigned pl = raw[i];
        int lnode = (pl >> ssh) & 63;
        int r = atomicAdd(&hist[lnode], 1);
        srt[hoff[lnode] + r] = pl;
    }
    __syncthreads();

    const int g    = tid >> 4;
    const int cq   = tid & 15;
    const int node = b * 64 + g;
    const unsigned smask = (1u << ssh) - 1;
    const ushort4* __restrict__ y4 = reinterpret_cast<const ushort4*>(y);

    float4 acc = make_float4(0.f, 0.f, 0.f, 0.f);
    const int s0 = hoff[g];
    const int s1 = hoff[g + 1];
    int p = s0;
    for (; p + 3 < s1; p += 4) {          // 4-deep: 4 independent L3 loads
        unsigned pl0 = srt[p];
        unsigned pl1 = srt[p + 1];
        unsigned pl2 = srt[p + 2];
        unsigned pl3 = srt[p + 3];
        ushort4 v0 = y4[((long)(pl0 >> tsh) * n_nodes + (pl0 & smask)) * 16 + cq];
        ushort4 v1 = y4[((long)(pl1 >> tsh) * n_nodes + (pl1 & smask)) * 16 + cq];
        ushort4 v2 = y4[((long)(pl2 >> tsh) * n_nodes + (pl2 & smask)) * 16 + cq];
        ushort4 v3 = y4[((long)(pl3 >> tsh) * n_nodes + (pl3 & smask)) * 16 + cq];
        acc.x += (bf2f(v0.x) + bf2f(v1.x)) + (bf2f(v2.x) + bf2f(v3.x));
        acc.y += (bf2f(v0.y) + bf2f(v1.y)) + (bf2f(v2.y) + bf2f(v3.y));
        acc.z += (bf2f(v0.z) + bf2f(v1.z)) + (bf2f(v2.z) + bf2f(v3.z));
        acc.w += (bf2f(v0.w) + bf2f(v1.w)) + (bf2f(v2.w) + bf2f(v3.w));
    }
    for (; p < s1; ++p) {
        unsigned pl = srt[p];
        ushort4 v = y4[((long)(pl >> tsh) * n_nodes + (pl & smask)) * 16 + cq];
        acc.x += bf2f(v.x); acc.y += bf2f(v.y);
        acc.z += bf2f(v.z); acc.w += bf2f(v.w);
    }

    // Spill drain (normally S == 0).
    const int S = cursor[nb];
    for (int i = 0; i < S; ++i) {
        int2 sp = spill[i];
        if (sp.x == b) {
            unsigned v = (unsigned)sp.y;
            if ((int)((v >> ssh) & 63) == g) {
                int src = (int)(v & smask);
                int t   = (int)(v >> tsh);
                ushort4 w = y4[((long)t * n_nodes + src) * 16 + cq];
                acc.x += bf2f(w.x); acc.y += bf2f(w.y);
                acc.z += bf2f(w.z); acc.w += bf2f(w.w);
            }
        }
    }

    if (node < n_nodes) {
        float4* o  = reinterpret_cast<float4*>(out) + (long)node * 16 + cq;
        float4 cur = *o;
        cur.x += acc.x; cur.y += acc.y; cur.z += acc.z; cur.w += acc.w;
        *o = cur;
    }
}

// --------------------- fallbacks (small workspace) -------------------------
__global__ __launch_bounds__(256) void gemm_root_kernel(
    const float* __restrict__ x, const float* __restrict__ root_w,
    const float* __restrict__ root_b, float* __restrict__ out, int n_nodes)
{
    __shared__ float xs[NT][65];
    __shared__ float ws[64][65];
    const int tid   = threadIdx.x;
    const int node0 = blockIdx.x * NT;
    #pragma unroll
    for (int i = 0; i < 4; ++i) {
        int v  = tid + i * 256;
        int r  = v >> 4;
        int cq = v & 15;
        float4 w4 = reinterpret_cast<const float4*>(root_w)[v];
        ws[r][cq * 4 + 0] = w4.x; ws[r][cq * 4 + 1] = w4.y;
        ws[r][cq * 4 + 2] = w4.z; ws[r][cq * 4 + 3] = w4.w;
        int node = node0 + r;
        float4 x4 = (node < n_nodes)
                        ? reinterpret_cast<const float4*>(x)[node * 16 + cq]
                        : make_float4(0.f, 0.f, 0.f, 0.f);
        xs[r][cq * 4 + 0] = x4.x; xs[r][cq * 4 + 1] = x4.y;
        xs[r][cq * 4 + 2] = x4.z; xs[r][cq * 4 + 3] = x4.w;
    }
    __syncthreads();
    const int tc = (tid & 15) * 4;
    const int tr = (tid >> 4) * 4;
    float acc[4][4];
    #pragma unroll
    for (int i = 0; i < 4; ++i)
        #pragma unroll
        for (int j = 0; j < 4; ++j) acc[i][j] = 0.f;
    #pragma unroll 4
    for (int k = 0; k < 64; ++k) {
        float xv[4], wv[4];
        #pragma unroll
        for (int i = 0; i < 4; ++i) xv[i] = xs[tr + i][k];
        #pragma unroll
        for (int j = 0; j < 4; ++j) wv[j] = ws[k][tc + j];
        #pragma unroll
        for (int i = 0; i < 4; ++i)
            #pragma unroll
            for (int j = 0; j < 4; ++j) acc[i][j] += xv[i] * wv[j];
    }
    #pragma unroll
    for (int i = 0; i < 4; ++i) {
        int node = node0 + tr + i;
        if (node < n_nodes) {
            float4 o = make_float4(acc[i][0] + root_b[tc + 0], acc[i][1] + root_b[tc + 1],
                                   acc[i][2] + root_b[tc + 2], acc[i][3] + root_b[tc + 3]);
            reinterpret_cast<float4*>(out)[node * 16 + (tc >> 2)] = o;
        }
    }
}

__global__ __launch_bounds__(256) void edge_direct_kernel(
    const float* __restrict__ x, const int* __restrict__ ei,
    const int* __restrict__ et, const float* __restrict__ weight,
    float* __restrict__ out, int n_edges)
{
    int gwave  = (int)((blockIdx.x * (long)blockDim.x + threadIdx.x) >> 6);
    int lane   = threadIdx.x & 63;
    int nwaves = (int)(((long)gridDim.x * blockDim.x) >> 6);
    for (int e = gwave; e < n_edges; e += nwaves) {
        int src  = ei[e];
        int dstn = ei[n_edges + e];
        int t    = et[e];
        float xv = x[src * 64 + lane];
        const float* __restrict__ W = weight + t * 4096;
        float acc = 0.f;
        #pragma unroll 8
        for (int k = 0; k < 64; ++k) {
            float xk = __shfl(xv, k);
            acc += xk * W[k * 64 + lane];
        }
        atomicAdd(&out[(long)dstn * 64 + lane], acc);
    }
}

extern "C" void kernel_launch(void* const* d_in, const int* in_sizes, int n_in,
                              void* d_out, int out_size, void* d_ws, size_t ws_size,
                              hipStream_t stream) {
    const float* x      = (const float*)d_in[0];
    const int*   ei     = (const int*)d_in[1];   // [2, E] int32
    const int*   et     = (const int*)d_in[2];   // [E]
    const float* weight = (const float*)d_in[3]; // [4, 64, 64]
    const float* root_w = (const float*)d_in[4]; // [64, 64]
    const float* root_b = (const float*)d_in[5]; // [64]
    float* out = (float*)d_out;

    const int n_nodes = in_sizes[0] / 64;
    const int n_edges = in_sizes[2];
    const int nb      = (n_nodes + 63) >> 6;
    const int nblk    = (n_edges + CHUNK - 1) / CHUNK;   // fill blocks

    int ssh = 1;
    while ((1 << ssh) < n_nodes) ++ssh;   // bits for src
    const int tsh = ssh + 6;              // 6 bits for local dst

    const size_t wt_bytes = 5 * 4096 * sizeof(unsigned short);   // 40 KB
    const size_t y_bytes  = (size_t)4 * n_nodes * 64 * sizeof(unsigned short);
    const size_t b_bytes  = wt_bytes + y_bytes +
        ((size_t)nb + 1 + 2 * (size_t)nblk * nb + (size_t)nb * CAPB
         + 2 * (size_t)n_edges) * 4;

    const int gemm_blocks = (n_nodes + 127) / 128;

    if (nb <= NBMAX1 && tsh + 2 <= 32 && ws_size >= b_bytes) {
        unsigned short* wt      = (unsigned short*)d_ws;
        unsigned short* y       = (unsigned short*)((char*)d_ws + wt_bytes);
        int*            cursor  = (int*)((char*)d_ws + wt_bytes + y_bytes); // nb+1
        int*            counts  = cursor + nb + 1;                // nblk*nb
        int*            starts  = counts + (size_t)nblk * nb;     // nblk*nb
        unsigned*       payload = (unsigned*)(starts + (size_t)nblk * nb);
        int2*           spill   = (int2*)(payload + (size_t)nb * CAPB);

        const int ph_blocks = max(nblk, (5 * 4096 + FTHR - 1) / FTHR);
        ph_kernel<<<ph_blocks, FTHR, 0, stream>>>(
            weight, root_w, wt, ei, counts, n_edges, nb, nblk);
        scanw_kernel<<<(nb * 64 + 255) / 256, 256, 0, stream>>>(
            counts, starts, cursor, nb, nblk);
        fused_fg_kernel<<<nblk + gemm_blocks, FTHR, 0, stream>>>(
            x, (const uint4*)wt, root_b, out, y, n_nodes,
            ei, et, starts, cursor, spill, payload,
            n_edges, nb, nblk, ssh, tsh);
        gatherb5_kernel<<<nb, 1024, 0, stream>>>(
            cursor, payload, spill, y, out, n_nodes, nb, ssh, tsh);
    } else {
        gemm_root_kernel<<<(n_nodes + NT - 1) / NT, 256, 0, stream>>>(
            x, root_w, root_b, out, n_nodes);
        edge_direct_kernel<<<4096, 256, 0, stream>>>(x, ei, et, weight, out, n_edges);
    }
}

// Round 18
// 63.562 us; speedup vs baseline: 2.8344x; 1.0120x over previous
//
#include <hip/hip_runtime.h>

#define NT 64
#define NBMAX1 1024   // max buckets for the fast path (nodes <= 65536)
#define CAPB 2048     // payload slots per bucket (mean ~1279 here)
#define CHUNK 8192    // edges per fill block
#define FTHR 512      // threads for fast-path kernels

typedef short bf16x8 __attribute__((ext_vector_type(8)));
typedef float f32x4  __attribute__((ext_vector_type(4)));

__device__ __forceinline__ unsigned short f2bf(float f) {
    unsigned u = __builtin_bit_cast(unsigned, f);
    unsigned r = (u + 0x7fffu + ((u >> 16) & 1u)) >> 16;   // round-nearest-even
    return (unsigned short)r;
}
__device__ __forceinline__ float bf2f(unsigned short h) {
    return __builtin_bit_cast(float, (unsigned)h << 16);
}
__device__ __forceinline__ unsigned pack2(float a, float b) {
    return (unsigned)f2bf(a) | ((unsigned)f2bf(b) << 16);
}

// ---------------------------------------------------------------------------
// ph: prep W (bf16, transposed [m][col][k], XOR-swizzled) on the first
// 20480 threads, AND per-chunk LDS histogram -> counts[blk*nb+b].
// ---------------------------------------------------------------------------
__global__ __launch_bounds__(FTHR) void ph_kernel(
    const float* __restrict__ weight, const float* __restrict__ root_w,
    unsigned short* __restrict__ wt,
    const int* __restrict__ ei, int* __restrict__ counts,
    int n_edges, int nb, int nblk)
{
    const int tid = threadIdx.x;
    int g = blockIdx.x * FTHR + tid;
    if (g < 5 * 4096) {
        int m = g >> 12, rem = g & 4095, c = rem >> 6, k = rem & 63;
        float v = (m < 4) ? weight[m * 4096 + k * 64 + c] : root_w[k * 64 + c];
        int byte = m * 8192 + c * 128 + ((k * 2) ^ ((c & 7) << 4));
        wt[byte >> 1] = f2bf(v);
    }
    if (blockIdx.x >= nblk) return;

    __shared__ int lh[NBMAX1];
    for (int i = tid; i < nb; i += FTHR) lh[i] = 0;
    __syncthreads();
    const int lo = blockIdx.x * CHUNK;
    const int hi = min(lo + CHUNK, n_edges);
    for (int e = lo + tid; e < hi; e += FTHR)
        atomicAdd(&lh[ei[n_edges + e] >> 6], 1);
    __syncthreads();
    for (int i = tid; i < nb; i += FTHR)
        counts[(size_t)blockIdx.x * nb + i] = lh[i];
}

// ---------------------------------------------------------------------------
// scanw: ONE WAVE PER BUCKET. shfl-scan across nblk chunks (rounds of 64).
// ---------------------------------------------------------------------------
__global__ __launch_bounds__(256) void scanw_kernel(
    const int* __restrict__ counts, int* __restrict__ starts,
    int* __restrict__ cursor, int nb, int nblk)
{
    if (blockIdx.x == 0 && threadIdx.x == 0) cursor[nb] = 0;
    const int w    = (blockIdx.x * 256 + threadIdx.x) >> 6;
    const int lane = threadIdx.x & 63;
    if (w >= nb) return;
    const int b = w;
    int base = 0;
    for (int r = 0; r * 64 < nblk; ++r) {
        int i = r * 64 + lane;
        int c = (i < nblk) ? counts[(size_t)i * nb + b] : 0;
        int s = c;
        #pragma unroll
        for (int d = 1; d < 64; d <<= 1) {
            int u = __shfl_up(s, d, 64);
            if (lane >= d) s += u;
        }
        if (i < nblk) starts[(size_t)i * nb + b] = base + s - c;
        base += __shfl(s, 63, 64);
    }
    if (lane == 0) cursor[b] = base;
}

// ---------------------------------------------------------------------------
// Fused fillC ∥ gemm (FTHR=512 threads).
//  FILL blocks: loff from ph's counts row (NO second histogram pass) via
//  wave-shfl scan (2 barriers), ranked LDS placement, contiguous run writes.
//  GEMM blocks: MFMA, 128-node tile, 8 waves, operand-swapped.
// payload = src | ldst<<ssh | type<<tsh
// ---------------------------------------------------------------------------
__global__ __launch_bounds__(FTHR) void fused_fg_kernel(
    const float* __restrict__ x, const uint4* __restrict__ wt4,
    const float* __restrict__ root_b,
    float* __restrict__ out, unsigned short* __restrict__ y, int n_nodes,
    const int* __restrict__ ei, const int* __restrict__ et,
    const int* __restrict__ counts, const int* __restrict__ starts,
    int* __restrict__ cursor,
    int2* __restrict__ spill, unsigned* __restrict__ payload,
    int n_edges, int nb, int nblk, int ssh, int tsh)
{
    __shared__ __align__(16) char smem[57344];   // 56 KB
    const int tid = threadIdx.x;

    if (blockIdx.x < nblk) {
        // ------------------------- FILL path -------------------------------
        unsigned*       pl   = (unsigned*)smem;                    // CHUNK (32KB)
        unsigned short* bkt  = (unsigned short*)(pl + CHUNK);      // CHUNK (16KB)
        int*            lh   = (int*)(bkt + CHUNK);                // NBMAX1 (4KB)
        int*            loff = lh + NBMAX1;                        // NBMAX1 (4KB)
        int*            tsum = (int*)bkt;   // aliased: used & consumed BEFORE bkt

        const int blk = blockIdx.x;
        const int lo  = blk * CHUNK;
        const int hi  = min(lo + CHUNK, n_edges);
        const int n   = hi - lo;
        const int* __restrict__ crow = counts + (size_t)blk * nb;
        const int* __restrict__ srow = starts + (size_t)blk * nb;

        for (int i = tid; i < nb; i += FTHR) lh[i] = 0;
        // wave-scan of this block's counts row -> loff (exclusive)
        {
            int i0 = 2 * tid, i1 = 2 * tid + 1;
            int v0 = (i0 < nb) ? crow[i0] : 0;
            int v1 = (i1 < nb) ? crow[i1] : 0;
            int s  = v0 + v1;
            int sc = s;
            #pragma unroll
            for (int d = 1; d < 64; d <<= 1) {
                int u = __shfl_up(sc, d, 64);
                if ((tid & 63) >= d) sc += u;
            }
            if ((tid & 63) == 63) tsum[tid >> 6] = sc;
            __syncthreads();
            int wbase = 0;
            for (int w2 = 0; w2 < (tid >> 6); ++w2) wbase += tsum[w2];
            int excl = wbase + sc - s;
            if (i0 < nb) loff[i0] = excl;
            if (i1 < nb) loff[i1] = excl + v0;
        }
        __syncthreads();   // lh zeroed + loff ready (tsum dead from here)

        // ranked placement into LDS; record bucket per slot
        for (int i = tid; i < n; i += FTHR) {
            int e   = lo + i;
            int src = ei[e];
            int dn  = ei[n_edges + e];
            int t   = et[e];
            int b   = dn >> 6;
            int r   = atomicAdd(&lh[b], 1);
            int slot = loff[b] + r;
            pl[slot]  = (unsigned)src | ((unsigned)(dn & 63) << ssh)
                      | ((unsigned)t << tsh);
            bkt[slot] = (unsigned short)b;
        }
        __syncthreads();

        // write out: direct bucket lookup; consecutive slots -> consecutive
        // payload addresses within each run.
        for (int i = tid; i < n; i += FTHR) {
            int b    = bkt[i];
            int rank = srow[b] + (i - loff[b]);
            unsigned v = pl[i];
            if (rank < CAPB) {
                payload[(size_t)b * CAPB + rank] = v;
            } else {
                int sp = atomicAdd(&cursor[nb], 1);
                spill[sp] = make_int2(b, (int)v);
            }
        }
        return;
    }

    // --------------------------- GEMM path (128-node tile) -----------------
    uint4* lds4 = (uint4*)smem;          // x: [0,1024) ; Wt: [1024,3584)
    const int node0 = (blockIdx.x - nblk) * 128;

    for (int i = tid; i < 2560; i += FTHR) lds4[1024 + i] = wt4[i];

    {
        int n    = tid >> 2;             // 0..127
        int kq   = tid & 3;
        int node = node0 + n;
        uint4 p0, p1;
        if (node < n_nodes) {
            const float4* src = reinterpret_cast<const float4*>(x)
                                + (size_t)node * 16 + kq * 4;
            float4 f0 = src[0], f1 = src[1], f2 = src[2], f3 = src[3];
            p0.x = pack2(f0.x, f0.y); p0.y = pack2(f0.z, f0.w);
            p0.z = pack2(f1.x, f1.y); p0.w = pack2(f1.z, f1.w);
            p1.x = pack2(f2.x, f2.y); p1.y = pack2(f2.z, f2.w);
            p1.z = pack2(f3.x, f3.y); p1.w = pack2(f3.z, f3.w);
        } else {
            p0 = make_uint4(0, 0, 0, 0);
            p1 = p0;
        }
        int s0 = (kq * 2) ^ (n & 7);
        lds4[n * 8 + s0]       = p0;
        lds4[n * 8 + (s0 ^ 1)] = p1;
    }
    __syncthreads();

    const int wv = tid >> 6;             // 0..7
    const int l  = tid & 63;
    const int lo = l & 15;
    const int hi = l >> 4;

    const int arow = (wv >> 2) * 64 + (wv & 3) * 16 + lo;   // 0..127
    bf16x8 xb0 = *reinterpret_cast<const bf16x8*>(
        &lds4[arow * 8 + ((0 + hi) ^ (arow & 7))]);
    bf16x8 xb1 = *reinterpret_cast<const bf16x8*>(
        &lds4[arow * 8 + ((4 + hi) ^ (arow & 7))]);

    const int node   = node0 + arow;
    const bool valid = (node < n_nodes);

    for (int m = 0; m < 5; ++m) {
        f32x4 acc[4];
        #pragma unroll
        for (int j = 0; j < 4; ++j)
            acc[j] = (f32x4){0.f, 0.f, 0.f, 0.f};

        #pragma unroll
        for (int j = 0; j < 4; ++j) {
            int c     = j * 16 + lo;
            int bbase = 1024 + m * 512 + c * 8;
            bf16x8 w0 = *reinterpret_cast<const bf16x8*>(
                &lds4[bbase + ((0 + hi) ^ (c & 7))]);
            acc[j] = __builtin_amdgcn_mfma_f32_16x16x32_bf16(w0, xb0, acc[j], 0, 0, 0);
            bf16x8 w1 = *reinterpret_cast<const bf16x8*>(
                &lds4[bbase + ((4 + hi) ^ (c & 7))]);
            acc[j] = __builtin_amdgcn_mfma_f32_16x16x32_bf16(w1, xb1, acc[j], 0, 0, 0);
        }

        if (m < 4) {
            if (valid) {
                unsigned short* __restrict__ ym = y + (size_t)m * n_nodes * 64;
                #pragma unroll
                for (int j = 0; j < 4; ++j) {
                    uint2 o;
                    o.x = pack2(acc[j][0], acc[j][1]);
                    o.y = pack2(acc[j][2], acc[j][3]);
                    *reinterpret_cast<uint2*>(
                        &ym[(size_t)node * 64 + j * 16 + hi * 4]) = o;
                }
            }
        } else {
            if (valid) {
                #pragma unroll
                for (int j = 0; j < 4; ++j) {
                    float4 rb = reinterpret_cast<const float4*>(root_b)[j * 4 + hi];
                    float4 o  = make_float4(acc[j][0] + rb.x, acc[j][1] + rb.y,
                                            acc[j][2] + rb.z, acc[j][3] + rb.w);
                    *reinterpret_cast<float4*>(
                        &out[(size_t)node * 64 + j * 16 + hi * 4]) = o;
                }
            }
        }
    }
}

// ---------------------------------------------------------------------------
// Gather: one 1024-thread block per bucket; in-LDS counting sort by local dst,
// 64 groups x 16 threads accumulate in registers (unroll x4). int2 spill.
// ---------------------------------------------------------------------------
__global__ __launch_bounds__(1024) void gatherb5_kernel(
    const int* __restrict__ cursor, const unsigned* __restrict__ payload,
    const int2* __restrict__ spill,
    const unsigned short* __restrict__ y, float* __restrict__ out,
    int n_nodes, int nb, int ssh, int tsh)
{
    __shared__ unsigned raw[CAPB];
    __shared__ unsigned srt[CAPB];
    __shared__ int hist[64];
    __shared__ int hoff[65];

    const int tid = threadIdx.x;
    const int b   = blockIdx.x;
    const int n_in = min(cursor[b], CAPB);
    const unsigned* __restrict__ pl_base = payload + (size_t)b * CAPB;

    if (tid < 64) hist[tid] = 0;
    __syncthreads();
    for (int i = tid; i < n_in; i += 1024) {
        unsigned pl = pl_base[i];
        raw[i] = pl;
        atomicAdd(&hist[(pl >> ssh) & 63], 1);
    }
    __syncthreads();
    if (tid < 64) {                       // wave-parallel exclusive scan
        int v = hist[tid];
        int s = v;
        #pragma unroll
        for (int d = 1; d < 64; d <<= 1) {
            int u = __shfl_up(s, d, 64);
            if (tid >= d) s += u;
        }
        hoff[tid] = s - v;
        if (tid == 63) hoff[64] = s;
        hist[tid] = 0;
    }
    __syncthreads();
    for (int i = tid; i < n_in; i += 1024) {
        unsigned pl = raw[i];
        int lnode = (pl >> ssh) & 63;
        int r = atomicAdd(&hist[lnode], 1);
        srt[hoff[lnode] + r] = pl;
    }
    __syncthreads();

    const int g    = tid >> 4;
    const int cq   = tid & 15;
    const int node = b * 64 + g;
    const unsigned smask = (1u << ssh) - 1;
    const ushort4* __restrict__ y4 = reinterpret_cast<const ushort4*>(y);

    float4 acc = make_float4(0.f, 0.f, 0.f, 0.f);
    const int s0 = hoff[g];
    const int s1 = hoff[g + 1];
    int p = s0;
    for (; p + 3 < s1; p += 4) {          // 4-deep: 4 independent L3 loads
        unsigned pl0 = srt[p];
        unsigned pl1 = srt[p + 1];
        unsigned pl2 = srt[p + 2];
        unsigned pl3 = srt[p + 3];
        ushort4 v0 = y4[((long)(pl0 >> tsh) * n_nodes + (pl0 & smask)) * 16 + cq];
        ushort4 v1 = y4[((long)(pl1 >> tsh) * n_nodes + (pl1 & smask)) * 16 + cq];
        ushort4 v2 = y4[((long)(pl2 >> tsh) * n_nodes + (pl2 & smask)) * 16 + cq];
        ushort4 v3 = y4[((long)(pl3 >> tsh) * n_nodes + (pl3 & smask)) * 16 + cq];
        acc.x += (bf2f(v0.x) + bf2f(v1.x)) + (bf2f(v2.x) + bf2f(v3.x));
        acc.y += (bf2f(v0.y) + bf2f(v1.y)) + (bf2f(v2.y) + bf2f(v3.y));
        acc.z += (bf2f(v0.z) + bf2f(v1.z)) + (bf2f(v2.z) + bf2f(v3.z));
        acc.w += (bf2f(v0.w) + bf2f(v1.w)) + (bf2f(v2.w) + bf2f(v3.w));
    }
    for (; p < s1; ++p) {
        unsigned pl = srt[p];
        ushort4 v = y4[((long)(pl >> tsh) * n_nodes + (pl & smask)) * 16 + cq];
        acc.x += bf2f(v.x); acc.y += bf2f(v.y);
        acc.z += bf2f(v.z); acc.w += bf2f(v.w);
    }

    // Spill drain (normally S == 0).
    const int S = cursor[nb];
    for (int i = 0; i < S; ++i) {
        int2 sp = spill[i];
        if (sp.x == b) {
            unsigned v = (unsigned)sp.y;
            if ((int)((v >> ssh) & 63) == g) {
                int src = (int)(v & smask);
                int t   = (int)(v >> tsh);
                ushort4 w = y4[((long)t * n_nodes + src) * 16 + cq];
                acc.x += bf2f(w.x); acc.y += bf2f(w.y);
                acc.z += bf2f(w.z); acc.w += bf2f(w.w);
            }
        }
    }

    if (node < n_nodes) {
        float4* o  = reinterpret_cast<float4*>(out) + (long)node * 16 + cq;
        float4 cur = *o;
        cur.x += acc.x; cur.y += acc.y; cur.z += acc.z; cur.w += acc.w;
        *o = cur;
    }
}

// --------------------- fallbacks (small workspace) -------------------------
__global__ __launch_bounds__(256) void gemm_root_kernel(
    const float* __restrict__ x, const float* __restrict__ root_w,
    const float* __restrict__ root_b, float* __restrict__ out, int n_nodes)
{
    __shared__ float xs[NT][65];
    __shared__ float ws[64][65];
    const int tid   = threadIdx.x;
    const int node0 = blockIdx.x * NT;
    #pragma unroll
    for (int i = 0; i < 4; ++i) {
        int v  = tid + i * 256;
        int r  = v >> 4;
        int cq = v & 15;
        float4 w4 = reinterpret_cast<const float4*>(root_w)[v];
        ws[r][cq * 4 + 0] = w4.x; ws[r][cq * 4 + 1] = w4.y;
        ws[r][cq * 4 + 2] = w4.z; ws[r][cq * 4 + 3] = w4.w;
        int node = node0 + r;
        float4 x4 = (node < n_nodes)
                        ? reinterpret_cast<const float4*>(x)[node * 16 + cq]
                        : make_float4(0.f, 0.f, 0.f, 0.f);
        xs[r][cq * 4 + 0] = x4.x; xs[r][cq * 4 + 1] = x4.y;
        xs[r][cq * 4 + 2] = x4.z; xs[r][cq * 4 + 3] = x4.w;
    }
    __syncthreads();
    const int tc = (tid & 15) * 4;
    const int tr = (tid >> 4) * 4;
    float acc[4][4];
    #pragma unroll
    for (int i = 0; i < 4; ++i)
        #pragma unroll
        for (int j = 0; j < 4; ++j) acc[i][j] = 0.f;
    #pragma unroll 4
    for (int k = 0; k < 64; ++k) {
        float xv[4], wv[4];
        #pragma unroll
        for (int i = 0; i < 4; ++i) xv[i] = xs[tr + i][k];
        #pragma unroll
        for (int j = 0; j < 4; ++j) wv[j] = ws[k][tc + j];
        #pragma unroll
        for (int i = 0; i < 4; ++i)
            #pragma unroll
            for (int j = 0; j < 4; ++j) acc[i][j] += xv[i] * wv[j];
    }
    #pragma unroll
    for (int i = 0; i < 4; ++i) {
        int node = node0 + tr + i;
        if (node < n_nodes) {
            float4 o = make_float4(acc[i][0] + root_b[tc + 0], acc[i][1] + root_b[tc + 1],
                                   acc[i][2] + root_b[tc + 2], acc[i][3] + root_b[tc + 3]);
            reinterpret_cast<float4*>(out)[node * 16 + (tc >> 2)] = o;
        }
    }
}

__global__ __launch_bounds__(256) void edge_direct_kernel(
    const float* __restrict__ x, const int* __restrict__ ei,
    const int* __restrict__ et, const float* __restrict__ weight,
    float* __restrict__ out, int n_edges)
{
    int gwave  = (int)((blockIdx.x * (long)blockDim.x + threadIdx.x) >> 6);
    int lane   = threadIdx.x & 63;
    int nwaves = (int)(((long)gridDim.x * blockDim.x) >> 6);
    for (int e = gwave; e < n_edges; e += nwaves) {
        int src  = ei[e];
        int dstn = ei[n_edges + e];
        int t    = et[e];
        float xv = x[src * 64 + lane];
        const float* __restrict__ W = weight + t * 4096;
        float acc = 0.f;
        #pragma unroll 8
        for (int k = 0; k < 64; ++k) {
            float xk = __shfl(xv, k);
            acc += xk * W[k * 64 + lane];
        }
        atomicAdd(&out[(long)dstn * 64 + lane], acc);
    }
}

extern "C" void kernel_launch(void* const* d_in, const int* in_sizes, int n_in,
                              void* d_out, int out_size, void* d_ws, size_t ws_size,
                              hipStream_t stream) {
    const float* x      = (const float*)d_in[0];
    const int*   ei     = (const int*)d_in[1];   // [2, E] int32
    const int*   et     = (const int*)d_in[2];   // [E]
    const float* weight = (const float*)d_in[3]; // [4, 64, 64]
    const float* root_w = (const float*)d_in[4]; // [64, 64]
    const float* root_b = (const float*)d_in[5]; // [64]
    float* out = (float*)d_out;

    const int n_nodes = in_sizes[0] / 64;
    const int n_edges = in_sizes[2];
    const int nb      = (n_nodes + 63) >> 6;
    const int nblk    = (n_edges + CHUNK - 1) / CHUNK;   // fill blocks

    int ssh = 1;
    while ((1 << ssh) < n_nodes) ++ssh;   // bits for src
    const int tsh = ssh + 6;              // 6 bits for local dst

    const size_t wt_bytes = 5 * 4096 * sizeof(unsigned short);   // 40 KB
    const size_t y_bytes  = (size_t)4 * n_nodes * 64 * sizeof(unsigned short);
    const size_t b_bytes  = wt_bytes + y_bytes +
        ((size_t)nb + 1 + 2 * (size_t)nblk * nb + (size_t)nb * CAPB
         + 2 * (size_t)n_edges) * 4;

    const int gemm_blocks = (n_nodes + 127) / 128;

    if (nb <= NBMAX1 && tsh + 2 <= 32 && ws_size >= b_bytes) {
        unsigned short* wt      = (unsigned short*)d_ws;
        unsigned short* y       = (unsigned short*)((char*)d_ws + wt_bytes);
        int*            cursor  = (int*)((char*)d_ws + wt_bytes + y_bytes); // nb+1
        int*            counts  = cursor + nb + 1;                // nblk*nb
        int*            starts  = counts + (size_t)nblk * nb;     // nblk*nb
        unsigned*       payload = (unsigned*)(starts + (size_t)nblk * nb);
        int2*           spill   = (int2*)(payload + (size_t)nb * CAPB);

        const int ph_blocks = max(nblk, (5 * 4096 + FTHR - 1) / FTHR);
        ph_kernel<<<ph_blocks, FTHR, 0, stream>>>(
            weight, root_w, wt, ei, counts, n_edges, nb, nblk);
        scanw_kernel<<<(nb * 64 + 255) / 256, 256, 0, stream>>>(
            counts, starts, cursor, nb, nblk);
        fused_fg_kernel<<<nblk + gemm_blocks, FTHR, 0, stream>>>(
            x, (const uint4*)wt, root_b, out, y, n_nodes,
            ei, et, counts, starts, cursor, spill, payload,
            n_edges, nb, nblk, ssh, tsh);
        gatherb5_kernel<<<nb, 1024, 0, stream>>>(
            cursor, payload, spill, y, out, n_nodes, nb, ssh, tsh);
    } else {
        gemm_root_kernel<<<(n_nodes + NT - 1) / NT, 256, 0, stream>>>(
            x, root_w, root_b, out, n_nodes);
        edge_direct_kernel<<<4096, 256, 0, stream>>>(x, ei, et, weight, out, n_edges);
    }
}